// Round 4
// baseline (1079.480 us; speedup 1.0000x reference)
//
#include <hip/hip_runtime.h>
#include <math.h>

#define BATCH 65536
#define KIN   784
#define HD    768

typedef float f32x4 __attribute__((ext_vector_type(4)));
typedef short s16x8 __attribute__((ext_vector_type(8)));

__device__ __forceinline__ float frelu(float x){ return x > 0.f ? x : 0.f; }

// packed bf16 convert: dst = {lo16=cvt(a), hi16=cvt(b)}
__device__ __forceinline__ unsigned int cvtpk(float a, float b){
    unsigned int r;
    asm("v_cvt_pk_bf16_f32 %0, %1, %2" : "=v"(r) : "v"(a), "v"(b));
    return r;
}

// bf16 RTNE from fp32 (host-side-quality scalar path, used in split_wT)
__device__ __forceinline__ unsigned short f2bf(float v){
    unsigned int u = __builtin_bit_cast(unsigned int, v);
    u += 0x7FFFu + ((u >> 16) & 1u);
    return (unsigned short)(u >> 16);
}
__device__ __forceinline__ float bf2f(unsigned short s){
    unsigned int u = ((unsigned int)s) << 16;
    return __builtin_bit_cast(float, u);
}

// ---------------------------------------------------------------------------
// Split+transpose W[K][N] fp32 -> WhT/WlT [N][KP] bf16 (zero-padded K..KP)
// ---------------------------------------------------------------------------
__global__ __launch_bounds__(256)
void split_wT(const float* __restrict__ W, unsigned short* __restrict__ WhT,
              unsigned short* __restrict__ WlT, int K, int N, int KP)
{
    int idx = blockIdx.x * 256 + threadIdx.x;
    if (idx >= N * KP) return;
    int n = idx / KP, k = idx - n * KP;
    float v = (k < K) ? W[(size_t)k * N + n] : 0.f;
    unsigned short h = f2bf(v);
    WhT[idx] = h;
    WlT[idx] = f2bf(v - bf2f(h));
}

// ---------------------------------------------------------------------------
// Split-bf16 MFMA GEMM, LDS double-buffered, ONE barrier per K-tile.
// 3 cross-products (AhBl + AlBh + AhBh) -> fp32-class accuracy.
// Swizzle: slot = (l4 ^ (row>>1)) & 3 on both write and read (conflict-free
// at 8-lane b128 granularity).
// MODE 0: epilogue writes h and fused BN column partials (per-block, fp32).
// MODE 1: A transformed by BN+ReLU at write-time; epilogue reduces dom_out.
// ---------------------------------------------------------------------------
template<int MODE>
__global__ __launch_bounds__(256, 2)
void gemm_split(const float* __restrict__ A,
                const unsigned short* __restrict__ BhT,
                const unsigned short* __restrict__ BlT,
                const float* __restrict__ bias,
                float* __restrict__ C,
                const float* __restrict__ scale, const float* __restrict__ shift,
                const float* __restrict__ Wd2, double* __restrict__ domacc,
                float* __restrict__ sp1, float* __restrict__ sp2,
                int K, int KP, int NT, int ldA)
{
    __shared__ __align__(16) char sm[65536];
    const int AH = 0, AL = 8192, BH = 16384, BL = 24576;  // within 32KB buffer

    int bid = blockIdx.x;
    int wg = (bid & 7) * 384 + (bid >> 3);      // XCD-contiguous remap
    int mb = wg / 6, nb = wg - mb * 6;
    int m0 = mb << 7, n0 = nb << 7;

    int tid = threadIdx.x;
    int lane = tid & 63, wid = tid >> 6;
    int wr = wid >> 1, wc = wid & 1;
    int l15 = lane & 15, l4 = lane >> 4;

    // fragment LDS byte offsets (relative to buffer base)
    int aoff[4], boff[4];
    #pragma unroll
    for (int f = 0; f < 4; f++) {
        int ra = wr * 64 + f * 16 + l15;
        aoff[f] = ra * 64 + (((l4 ^ (ra >> 1)) & 3) << 4);
        int rb = wc * 64 + f * 16 + l15;
        boff[f] = rb * 64 + (((l4 ^ (rb >> 1)) & 3) << 4);
    }

    // staging decompositions
    int ac_r[4], ac_s[4];
    #pragma unroll
    for (int q = 0; q < 4; q++) { int c = q * 256 + tid; ac_r[q] = c >> 3; ac_s[q] = c & 7; }
    int bc_r[2], bc_s[2];
    #pragma unroll
    for (int q = 0; q < 2; q++) { int c = q * 256 + tid; bc_r[q] = c >> 2; bc_s[q] = c & 3; }

    f32x4 acc[4][4];
    #pragma unroll
    for (int i = 0; i < 4; i++)
        #pragma unroll
        for (int j = 0; j < 4; j++) acc[i][j] = (f32x4){0.f, 0.f, 0.f, 0.f};

    float4 av[4], asc[4], ash[4];
    s16x8 bvh[2], bvl[2];

    auto loadA = [&](int t) {          // pure load-issue; no dependent VALU
        #pragma unroll
        for (int q = 0; q < 4; q++) {
            int kk = t * 32 + ac_s[q] * 4;
            if (kk < K) {
                av[q] = *(const float4*)(A + (size_t)(m0 + ac_r[q]) * ldA + kk);
                if (MODE == 1) {
                    asc[q] = *(const float4*)(scale + kk);
                    ash[q] = *(const float4*)(shift + kk);
                }
            }
        }
    };
    auto loadB = [&](int t) {
        #pragma unroll
        for (int q = 0; q < 2; q++) {
            size_t go = (size_t)(n0 + bc_r[q]) * KP + t * 32 + bc_s[q] * 8;
            bvh[q] = *(const s16x8*)(BhT + go);
            bvl[q] = *(const s16x8*)(BlT + go);
        }
    };
    auto writeA = [&](int t, int buf) { // transform + split + swizzled store
        #pragma unroll
        for (int q = 0; q < 4; q++) {
            int kk = t * 32 + ac_s[q] * 4;
            float4 v = av[q];
            if (MODE == 1) {
                v.x = frelu(v.x * asc[q].x + ash[q].x);
                v.y = frelu(v.y * asc[q].y + ash[q].y);
                v.z = frelu(v.z * asc[q].z + ash[q].z);
                v.w = frelu(v.w * asc[q].w + ash[q].w);
            }
            if (kk >= K) v = make_float4(0.f, 0.f, 0.f, 0.f);
            unsigned int h0 = cvtpk(v.x, v.y), h1 = cvtpk(v.z, v.w);
            float hx = __builtin_bit_cast(float, h0 << 16);
            float hy = __builtin_bit_cast(float, h0 & 0xFFFF0000u);
            float hz = __builtin_bit_cast(float, h1 << 16);
            float hw = __builtin_bit_cast(float, h1 & 0xFFFF0000u);
            unsigned int l0 = cvtpk(v.x - hx, v.y - hy), l1 = cvtpk(v.z - hz, v.w - hw);
            int r = ac_r[q], s = ac_s[q];
            int addr = (buf << 15) + AH + r * 64 + ((((s >> 1) ^ (r >> 1)) & 3) << 4) + ((s & 1) << 3);
            *(uint2*)(sm + addr)            = make_uint2(h0, h1);
            *(uint2*)(sm + addr + (AL - AH)) = make_uint2(l0, l1);
        }
    };
    auto writeB = [&](int buf) {
        #pragma unroll
        for (int q = 0; q < 2; q++) {
            int r = bc_r[q], s = bc_s[q];
            int addr = (buf << 15) + BH + r * 64 + (((s ^ (r >> 1)) & 3) << 4);
            *(s16x8*)(sm + addr)            = bvh[q];
            *(s16x8*)(sm + addr + (BL - BH)) = bvl[q];
        }
    };

    // prologue: stage tile0 into buf0, prefetch tile1 into regs
    loadA(0); loadB(0);
    writeA(0, 0); writeB(0);
    loadA(1); loadB(1);
    __syncthreads();

    int cur = 0;
    for (int t = 0; t < NT; t++) {
        if (t + 1 < NT) { writeA(t + 1, cur ^ 1); writeB(cur ^ 1); }
        if (t + 2 < NT) { loadA(t + 2); loadB(t + 2); }
        const char* sb = sm + (cur << 15);
        s16x8 fah[4], fal[4], fbh[4], fbl[4];
        #pragma unroll
        for (int f = 0; f < 4; f++) {
            fah[f] = *(const s16x8*)(sb + AH + aoff[f]);
            fal[f] = *(const s16x8*)(sb + AL + aoff[f]);
            fbh[f] = *(const s16x8*)(sb + BH + boff[f]);
            fbl[f] = *(const s16x8*)(sb + BL + boff[f]);
        }
        #pragma unroll
        for (int i = 0; i < 4; i++)
            #pragma unroll
            for (int j = 0; j < 4; j++) {
                acc[i][j] = __builtin_amdgcn_mfma_f32_16x16x32_bf16(fah[i], fbl[j], acc[i][j], 0, 0, 0);
                acc[i][j] = __builtin_amdgcn_mfma_f32_16x16x32_bf16(fal[i], fbh[j], acc[i][j], 0, 0, 0);
                acc[i][j] = __builtin_amdgcn_mfma_f32_16x16x32_bf16(fah[i], fbh[j], acc[i][j], 0, 0, 0);
            }
        __syncthreads();
        cur ^= 1;
    }

    if (MODE == 0) {
        float bc[4];
        #pragma unroll
        for (int f = 0; f < 4; f++) bc[f] = bias[n0 + wc * 64 + f * 16 + l15];
        float cs[4] = {0.f,0.f,0.f,0.f}, cq[4] = {0.f,0.f,0.f,0.f};
        #pragma unroll
        for (int i = 0; i < 4; i++) {
            int rowb = m0 + wr * 64 + i * 16 + l4 * 4;
            #pragma unroll
            for (int j2 = 0; j2 < 4; j2++) {
                float* crow = C + (size_t)(rowb + j2) * HD + n0 + wc * 64 + l15;
                #pragma unroll
                for (int f = 0; f < 4; f++) {
                    float v = acc[i][f][j2] + bc[f];
                    crow[f * 16] = v;
                    cs[f] += v; cq[f] += v * v;
                }
            }
        }
        #pragma unroll
        for (int m = 16; m < 64; m <<= 1)
            #pragma unroll
            for (int f = 0; f < 4; f++) {
                cs[f] += __shfl_xor(cs[f], m, 64);
                cq[f] += __shfl_xor(cq[f], m, 64);
            }
        if (l4 == 0) {
            #pragma unroll
            for (int f = 0; f < 4; f++) {
                int col = n0 + wc * 64 + f * 16 + l15;
                sp1[(size_t)col * 1024 + mb * 2 + wr] = cs[f];
                sp2[(size_t)col * 1024 + mb * 2 + wr] = cq[f];
            }
        }
    } else {
        float bc[4], w2[4][3];
        #pragma unroll
        for (int f = 0; f < 4; f++) {
            int col = n0 + wc * 64 + f * 16 + l15;
            bc[f] = bias[col];
            w2[f][0] = Wd2[col * 3 + 0]; w2[f][1] = Wd2[col * 3 + 1]; w2[f][2] = Wd2[col * 3 + 2];
        }
        float s0[16], s1[16], s2[16];
        #pragma unroll
        for (int i = 0; i < 16; i++) { s0[i] = 0.f; s1[i] = 0.f; s2[i] = 0.f; }
        #pragma unroll
        for (int i = 0; i < 4; i++)
            #pragma unroll
            for (int j2 = 0; j2 < 4; j2++) {
                int idx = i * 4 + j2;
                #pragma unroll
                for (int f = 0; f < 4; f++) {
                    float v = frelu(acc[i][f][j2] + bc[f]);
                    s0[idx] += v * w2[f][0];
                    s1[idx] += v * w2[f][1];
                    s2[idx] += v * w2[f][2];
                }
            }
        #pragma unroll
        for (int m = 1; m < 16; m <<= 1) {
            #pragma unroll
            for (int i = 0; i < 16; i++) {
                s0[i] += __shfl_xor(s0[i], m, 64);
                s1[i] += __shfl_xor(s1[i], m, 64);
                s2[i] += __shfl_xor(s2[i], m, 64);
            }
        }
        if (l15 == 0) {
            #pragma unroll
            for (int i = 0; i < 16; i++) {
                int row = m0 + wr * 64 + (i >> 2) * 16 + l4 * 4 + (i & 3);
                atomicAdd(&domacc[(size_t)row * 3 + 0], (double)s0[i]);
                atomicAdd(&domacc[(size_t)row * 3 + 1], (double)s1[i]);
                atomicAdd(&domacc[(size_t)row * 3 + 2], (double)s2[i]);
            }
        }
    }
}

// ---- BN final: reduce 1024 fp32 partials per column in fp64 ----------------
__global__ __launch_bounds__(256)
void bnfinal(const float* __restrict__ sp1, const float* __restrict__ sp2,
             const float* __restrict__ gamma, const float* __restrict__ beta,
             float* __restrict__ scale, float* __restrict__ shift)
{
    int c = blockIdx.x, t = threadIdx.x;
    const float* p1 = sp1 + (size_t)c * 1024;
    const float* p2 = sp2 + (size_t)c * 1024;
    double S = (double)p1[t] + (double)p1[t + 256] + (double)p1[t + 512] + (double)p1[t + 768];
    double Q = (double)p2[t] + (double)p2[t + 256] + (double)p2[t + 512] + (double)p2[t + 768];
    #pragma unroll
    for (int m = 1; m < 64; m <<= 1) { S += __shfl_xor(S, m, 64); Q += __shfl_xor(Q, m, 64); }
    __shared__ double sd1[4], sd2[4];
    int w = t >> 6;
    if ((t & 63) == 0) { sd1[w] = S; sd2[w] = Q; }
    __syncthreads();
    if (t == 0) {
        double Sa = sd1[0] + sd1[1] + sd1[2] + sd1[3];
        double Qa = sd2[0] + sd2[1] + sd2[2] + sd2[3];
        double mu  = Sa * (1.0 / 65536.0);
        double var = Qa * (1.0 / 65536.0) - mu * mu;
        double inv = 1.0 / sqrt(var + 1e-5);
        double sc  = inv * (double)gamma[c];
        double sh  = (double)beta[c] - mu * sc;
        scale[c] = (float)sc;
        shift[c] = (float)sh;
    }
}

// ---- dom_out finalize pass A: write outdom, flag borderline rows -----------
__global__ __launch_bounds__(256)
void domfinal_a(const double* __restrict__ domacc, const float* __restrict__ bd2,
                float* __restrict__ outdom, int* __restrict__ fixmeta, int* __restrict__ fixlist)
{
    int r = blockIdx.x * 256 + threadIdx.x;
    double v0 = domacc[(size_t)r * 3 + 0] + (double)bd2[0];
    double v1 = domacc[(size_t)r * 3 + 1] + (double)bd2[1];
    double v2 = domacc[(size_t)r * 3 + 2] + (double)bd2[2];
    outdom[(size_t)r * 3 + 0] = (float)v0;
    outdom[(size_t)r * 3 + 1] = (float)v1;
    outdom[(size_t)r * 3 + 2] = (float)v2;
    double mx01 = v0 > v1 ? v0 : v1, mn01 = v0 > v1 ? v1 : v0;
    double best = mx01 > v2 ? mx01 : v2;
    double m2   = mx01 > v2 ? (mn01 > v2 ? mn01 : v2) : mx01;
    if (best - m2 < 1e-3) {
        int p = atomicAdd(fixmeta, 1);
        fixlist[p] = r;
    }
}

// ---- exact fp32 recompute of dom_out for borderline rows (16 rows/block) ---
__global__ __launch_bounds__(256)
void fixrow(const int* __restrict__ fixmeta, const int* __restrict__ fixlist,
            const float* __restrict__ hbuf, const float* __restrict__ scale,
            const float* __restrict__ shift, const float* __restrict__ Wd1,
            const float* __restrict__ bd1, const float* __restrict__ Wd2,
            const float* __restrict__ bd2, float* __restrict__ outdom)
{
    int nfix = fixmeta[0];
    __shared__ float feat[16][HD];
    __shared__ float red[4][3];
    int tid = threadIdx.x;
    for (int base = blockIdx.x * 16; base < nfix; base += gridDim.x * 16) {
        int nr = nfix - base; if (nr > 16) nr = 16;
        __syncthreads();
        for (int i = tid; i < nr * HD; i += 256) {
            int rr = i / HD, c = i - rr * HD;
            int row = fixlist[base + rr];
            feat[rr][c] = frelu(hbuf[(size_t)row * HD + c] * scale[c] + shift[c]);
        }
        __syncthreads();
        int n0 = tid * 3;
        float acc[16][3];
        #pragma unroll
        for (int rr = 0; rr < 16; rr++) { acc[rr][0] = 0.f; acc[rr][1] = 0.f; acc[rr][2] = 0.f; }
        for (int k = 0; k < HD; k++) {
            float w0 = Wd1[(size_t)k * HD + n0];
            float w1 = Wd1[(size_t)k * HD + n0 + 1];
            float w2 = Wd1[(size_t)k * HD + n0 + 2];
            #pragma unroll
            for (int rr = 0; rr < 16; rr++) {
                float fv = feat[rr][k];
                acc[rr][0] += fv * w0; acc[rr][1] += fv * w1; acc[rr][2] += fv * w2;
            }
        }
        float b0 = bd1[n0], b1 = bd1[n0 + 1], b2 = bd1[n0 + 2];
        float wa[3][3];
        #pragma unroll
        for (int i = 0; i < 3; i++)
            #pragma unroll
            for (int d = 0; d < 3; d++) wa[i][d] = Wd2[(n0 + i) * 3 + d];
        #pragma unroll
        for (int rr = 0; rr < 16; rr++) {
            if (rr >= nr) break;
            float h0 = frelu(acc[rr][0] + b0);
            float h1 = frelu(acc[rr][1] + b1);
            float h2 = frelu(acc[rr][2] + b2);
            float y0 = h0 * wa[0][0] + h1 * wa[1][0] + h2 * wa[2][0];
            float y1 = h0 * wa[0][1] + h1 * wa[1][1] + h2 * wa[2][1];
            float y2 = h0 * wa[0][2] + h1 * wa[1][2] + h2 * wa[2][2];
            #pragma unroll
            for (int m = 1; m < 64; m <<= 1) {
                y0 += __shfl_xor(y0, m, 64);
                y1 += __shfl_xor(y1, m, 64);
                y2 += __shfl_xor(y2, m, 64);
            }
            if ((tid & 63) == 0) { red[tid >> 6][0] = y0; red[tid >> 6][1] = y1; red[tid >> 6][2] = y2; }
            __syncthreads();
            if (tid == 0) {
                int row = fixlist[base + rr];
                double v0 = (double)red[0][0] + red[1][0] + red[2][0] + red[3][0] + (double)bd2[0];
                double v1 = (double)red[0][1] + red[1][1] + red[2][1] + red[3][1] + (double)bd2[1];
                double v2 = (double)red[0][2] + red[1][2] + red[2][2] + red[3][2] + (double)bd2[2];
                outdom[(size_t)row * 3 + 0] = (float)v0;
                outdom[(size_t)row * 3 + 1] = (float)v1;
                outdom[(size_t)row * 3 + 2] = (float)v2;
            }
            __syncthreads();
        }
    }
}

// ---- pass B: argmax + bucket. Block-aggregated: 3 global atomics per block -
__global__ __launch_bounds__(256)
void domfinal_b(const float* __restrict__ outdom, int* __restrict__ cnt, int* __restrict__ lists)
{
    __shared__ int lcnt[3], base[3];
    int tid = threadIdx.x;
    if (tid < 3) lcnt[tid] = 0;
    __syncthreads();
    int r = blockIdx.x * 256 + tid;
    float v0 = outdom[(size_t)r * 3 + 0];
    float v1 = outdom[(size_t)r * 3 + 1];
    float v2 = outdom[(size_t)r * 3 + 2];
    int p = 0; float best = v0;
    if (v1 > best) { best = v1; p = 1; }
    if (v2 > best) { best = v2; p = 2; }
    int lpos = atomicAdd(&lcnt[p], 1);
    __syncthreads();
    if (tid < 3) base[tid] = atomicAdd(&cnt[tid], lcnt[tid]);
    __syncthreads();
    lists[(size_t)p * BATCH + base[p] + lpos] = r;
}

// ---- expert MLP: 32 same-domain rows per block, Wa staged through LDS ------
__global__ __launch_bounds__(256)
void expert_kernel(const float* __restrict__ h, const float* __restrict__ scale, const float* __restrict__ shift,
                   const int* __restrict__ cnt, const int* __restrict__ lists,
                   const float* __restrict__ Wa, const float* __restrict__ ba,
                   const float* __restrict__ Wb, const float* __restrict__ bb,
                   float* __restrict__ outs)
{
    int d = blockIdx.y;
    int start = blockIdx.x * 32;
    int count = cnt[d];
    if (start >= count) return;
    int nrows = count - start; if (nrows > 32) nrows = 32;

    __shared__ int   rowidx[32];
    __shared__ float fs[32][68];
    __shared__ float wsa[64][64];
    __shared__ float hid[32][64];

    int tid = threadIdx.x;
    if (tid < 32) {
        int i = tid < nrows ? tid : (nrows - 1);
        rowidx[tid] = lists[(size_t)d * BATCH + start + i];
    }
    __syncthreads();

    int rr = tid >> 3;
    int g  = tid & 7;
    int fcol = g << 3;

    float hacc[8] = {0, 0, 0, 0, 0, 0, 0, 0};

    for (int k0 = 0; k0 < HD; k0 += 64) {
        {
            int row = rowidx[rr];
            const float* hp  = h + (size_t)row * HD + k0 + fcol;
            const float* scp = scale + k0 + fcol;
            const float* shp = shift + k0 + fcol;
            float4 v0 = *(const float4*)hp;
            float4 v1 = *(const float4*)(hp + 4);
            fs[rr][fcol + 0] = frelu(v0.x * scp[0] + shp[0]);
            fs[rr][fcol + 1] = frelu(v0.y * scp[1] + shp[1]);
            fs[rr][fcol + 2] = frelu(v0.z * scp[2] + shp[2]);
            fs[rr][fcol + 3] = frelu(v0.w * scp[3] + shp[3]);
            fs[rr][fcol + 4] = frelu(v1.x * scp[4] + shp[4]);
            fs[rr][fcol + 5] = frelu(v1.y * scp[5] + shp[5]);
            fs[rr][fcol + 6] = frelu(v1.z * scp[6] + shp[6]);
            fs[rr][fcol + 7] = frelu(v1.w * scp[7] + shp[7]);
        }
        #pragma unroll
        for (int rep = 0; rep < 4; rep++) {
            int idx = rep * 256 + tid;
            int kk = idx >> 4;
            int f4 = (idx & 15) << 2;
            *(float4*)&wsa[kk][f4] = *(const float4*)(Wa + ((size_t)d * HD + k0 + kk) * 64 + f4);
        }
        __syncthreads();
        #pragma unroll 8
        for (int kk = 0; kk < 64; kk++) {
            float fv = fs[rr][kk];
            const float* wrow = &wsa[kk][g << 3];
            float4 w0 = *(const float4*)wrow;
            float4 w1 = *(const float4*)(wrow + 4);
            hacc[0] += fv * w0.x; hacc[1] += fv * w0.y; hacc[2] += fv * w0.z; hacc[3] += fv * w0.w;
            hacc[4] += fv * w1.x; hacc[5] += fv * w1.y; hacc[6] += fv * w1.z; hacc[7] += fv * w1.w;
        }
        __syncthreads();
    }

    #pragma unroll
    for (int j = 0; j < 8; j++) {
        float v = hacc[j] + ba[d * 64 + fcol + j];
        hid[rr][fcol + j] = frelu(v);
    }
    __syncthreads();

    for (int o = tid; o < 320; o += 256) {
        int r2 = o / 10, c = o - r2 * 10;
        if (r2 < nrows) {
            float s = 0.f;
            #pragma unroll 16
            for (int l = 0; l < 64; l++) s += hid[r2][l] * Wb[((size_t)d * 64 + l) * 10 + c];
            outs[(size_t)rowidx[r2] * 10 + c] = s + bb[d * 10 + c];
        }
    }
}

// ---------------------------------------------------------------------------
extern "C" void kernel_launch(void* const* d_in, const int* in_sizes, int n_in,
                              void* d_out, int out_size, void* d_ws, size_t ws_size,
                              hipStream_t stream)
{
    const float* x     = (const float*)d_in[0];
    const float* W1    = (const float*)d_in[1];
    const float* b1    = (const float*)d_in[2];
    const float* gamma = (const float*)d_in[3];
    const float* beta  = (const float*)d_in[4];
    const float* Wd1   = (const float*)d_in[5];
    const float* bd1   = (const float*)d_in[6];
    const float* Wd2   = (const float*)d_in[7];
    const float* bd2   = (const float*)d_in[8];
    const float* Wa    = (const float*)d_in[9];
    const float* ba    = (const float*)d_in[10];
    const float* Wb    = (const float*)d_in[11];
    const float* bb    = (const float*)d_in[12];

    float* out    = (float*)d_out;
    float* outs   = out;
    float* outdom = out + (size_t)BATCH * 10;

    char* ws = (char*)d_ws;
    size_t off = 0;
    float*  h      = (float*)(ws + off);            off += (size_t)BATCH * HD * 4;
    unsigned short* W1hT  = (unsigned short*)(ws + off); off += (size_t)HD * 800 * 2;
    unsigned short* W1lT  = (unsigned short*)(ws + off); off += (size_t)HD * 800 * 2;
    unsigned short* Wd1hT = (unsigned short*)(ws + off); off += (size_t)HD * HD * 2;
    unsigned short* Wd1lT = (unsigned short*)(ws + off); off += (size_t)HD * HD * 2;
    float*  sp1    = (float*)(ws + off);            off += (size_t)HD * 1024 * 4;
    float*  sp2    = (float*)(ws + off);            off += (size_t)HD * 1024 * 4;
    float*  scale  = (float*)(ws + off);            off += HD * 4;
    float*  shift  = (float*)(ws + off);            off += HD * 4;
    size_t zoff = off;
    double* domacc = (double*)(ws + off);           off += (size_t)BATCH * 3 * 8;
    int*    cnt    = (int*)(ws + off);              off += 64;
    int*    fixmeta= (int*)(ws + off);              off += 64;
    size_t zbytes = off - zoff;
    int*    lists  = (int*)(ws + off);              off += (size_t)3 * BATCH * 4;
    int*    fixlist= (int*)(ws + off);              off += (size_t)BATCH * 4;

    hipMemsetAsync(ws + zoff, 0, zbytes, stream);

    split_wT<<<(HD * 800) / 256, 256, 0, stream>>>(W1, W1hT, W1lT, KIN, HD, 800);
    split_wT<<<(HD * HD) / 256, 256, 0, stream>>>(Wd1, Wd1hT, Wd1lT, HD, HD, HD);

    gemm_split<0><<<3072, 256, 0, stream>>>(x, W1hT, W1lT, b1, h,
                                            nullptr, nullptr, nullptr, nullptr,
                                            sp1, sp2, KIN, 800, 25, KIN);
    bnfinal<<<HD, 256, 0, stream>>>(sp1, sp2, gamma, beta, scale, shift);
    gemm_split<1><<<3072, 256, 0, stream>>>(h, Wd1hT, Wd1lT, bd1, nullptr,
                                            scale, shift, Wd2, domacc,
                                            nullptr, nullptr, HD, HD, 24, HD);
    domfinal_a<<<BATCH / 256, 256, 0, stream>>>(domacc, bd2, outdom, fixmeta, fixlist);
    fixrow<<<16, 256, 0, stream>>>(fixmeta, fixlist, h, scale, shift, Wd1, bd1, Wd2, bd2, outdom);
    domfinal_b<<<BATCH / 256, 256, 0, stream>>>(outdom, cnt, lists);
    dim3 eg(BATCH / 32, 3);
    expert_kernel<<<eg, 256, 0, stream>>>(h, scale, shift, cnt, lists,
                                          Wa, ba, Wb, bb, outs);
}

// Round 6
// 880.572 us; speedup vs baseline: 1.2259x; 1.2259x over previous
//
#include <hip/hip_runtime.h>
#include <math.h>

#define BATCH 65536
#define KIN   784
#define HD    768

typedef float f32x4 __attribute__((ext_vector_type(4)));
typedef short s16x8 __attribute__((ext_vector_type(8)));
typedef unsigned int __attribute__((address_space(3))) lds_u32;
typedef const unsigned int __attribute__((address_space(1))) glb_u32;

__device__ __forceinline__ float frelu(float x){ return x > 0.f ? x : 0.f; }

// packed bf16 convert: dst = {lo16=cvt(a), hi16=cvt(b)}
__device__ __forceinline__ unsigned int cvtpk(float a, float b){
    unsigned int r;
    asm("v_cvt_pk_bf16_f32 %0, %1, %2" : "=v"(r) : "v"(a), "v"(b));
    return r;
}

__device__ __forceinline__ unsigned short f2bf(float v){
    unsigned int u = __builtin_bit_cast(unsigned int, v);
    u += 0x7FFFu + ((u >> 16) & 1u);
    return (unsigned short)(u >> 16);
}
__device__ __forceinline__ float bf2f(unsigned short s){
    unsigned int u = ((unsigned int)s) << 16;
    return __builtin_bit_cast(float, u);
}

__device__ __forceinline__ void gload16(const void* g, void* l){
    __builtin_amdgcn_global_load_lds((glb_u32*)g, (lds_u32*)l, 16, 0, 0);
}

// ---------------------------------------------------------------------------
// Pre-tile W[K][N] fp32 into per-(nb,t) 8KB chunks holding the EXACT swizzled
// LDS image: byte (r*64 + p*16 + e*2) of chunk (nb,t) = bf16 of
// W[t*32 + s*8 + e][nb*128 + r], s = p ^ ((r>>1)&3).  hi and lo arrays.
// ---------------------------------------------------------------------------
__global__ __launch_bounds__(256)
void tileW(const float* __restrict__ W, char* __restrict__ Wh, char* __restrict__ Wl,
           int K, int N, int NT)
{
    int chunk = blockIdx.x;
    int nb = chunk / NT, t = chunk - nb * NT;
    int tid = threadIdx.x;
    #pragma unroll
    for (int q = 0; q < 2; q++) {
        int idx = q * 256 + tid;
        int r = idx >> 2, p = idx & 3;
        int s = (p ^ ((r >> 1) & 3)) & 3;
        int kb = t * 32 + s * 8;
        int n = nb * 128 + r;
        s16x8 hv, lv;
        #pragma unroll
        for (int e = 0; e < 8; e++) {
            int k = kb + e;
            float v = (k < K) ? W[(size_t)k * N + n] : 0.f;
            unsigned short h = f2bf(v);
            hv[e] = (short)h;
            lv[e] = (short)f2bf(v - bf2f(h));
        }
        *(s16x8*)(Wh + (size_t)chunk * 8192 + idx * 16) = hv;
        *(s16x8*)(Wl + (size_t)chunk * 8192 + idx * 16) = lv;
    }
}

// ---------------------------------------------------------------------------
// Split-bf16 MFMA GEMM. B staged via global_load_lds from pre-tiled swizzled
// chunks. A reg-staged: fp32 load (k-permuted = source-side swizzle), LINEAR
// ds_write. m97 2-barrier loop, tile 128x128, BK=32, 4 waves (2x2).
// MODE 0 (GEMM1): 3-product Ah*Bl + Al*Bh + Ah*Bh -> h accurate to ~1e-5
//   (h feeds the argmax chain; fixrow recomputes from it). Epilogue: C=acc+
//   bias -> h + fused BN column partials.
// MODE 1 (GEMM2): 2-product Ah*(Bh+Bl); BN+ReLU fused at A-write; error
//   ~5e-4 in dom_out, caught by the 8e-3 fixrow net. Epilogue: a=relu(acc+
//   bd1); domacc += a @ Wd2 (shfl + fp64 atomics).
// ---------------------------------------------------------------------------
template<int MODE>
__global__ __launch_bounds__(256, 3)
void gemm2p(const float* __restrict__ A,
            const char* __restrict__ BhC, const char* __restrict__ BlC,
            const float* __restrict__ bias,
            float* __restrict__ C,
            const float* __restrict__ scale, const float* __restrict__ shift,
            const float* __restrict__ Wd2, double* __restrict__ domacc,
            float* __restrict__ sp1, float* __restrict__ sp2,
            int K, int NT, int ldA)
{
    constexpr int AH = 0;
    constexpr int AL = 8192;                       // MODE 0 only
    constexpr int BH = (MODE == 0) ? 16384 : 8192;
    constexpr int BL = BH + 8192;
    constexpr int SS = 24576;                      // MODE 1 only
    constexpr int SH = 27648;
    __shared__ __align__(16) char sm[(MODE == 0) ? 32768 : 30720];

    int bid = blockIdx.x;
    int wg = (bid & 7) * 384 + (bid >> 3);      // XCD-contiguous remap
    int mb = wg / 6, nb = wg - mb * 6;
    int m0 = mb << 7, n0 = nb << 7;

    int tid = threadIdx.x;
    int lane = tid & 63, wid = tid >> 6;
    int wr = wid >> 1, wc = wid & 1;
    int l15 = lane & 15, l4 = lane >> 4;

    // fragment LDS byte offsets: logical k-slot l4 at phys slot l4^((row>>1)&3)
    int aoff[4], boff[4];
    #pragma unroll
    for (int f = 0; f < 4; f++) {
        int ra = wr * 64 + f * 16 + l15;
        aoff[f] = ra * 64 + (((l4 ^ (ra >> 1)) & 3) << 4);
        int rb = wc * 64 + f * 16 + l15;
        boff[f] = rb * 64 + (((l4 ^ (rb >> 1)) & 3) << 4);
    }

    // A staging decomposition: idx = q*256+tid covers 512 x 16B groups
    int ar[2], akb0[2];
    #pragma unroll
    for (int q = 0; q < 2; q++) {
        int idx = q * 256 + tid;
        int r = idx >> 2, p = idx & 3;
        int s = (p ^ ((r >> 1) & 3)) & 3;
        ar[q] = r; akb0[q] = s * 8;
    }

    if (MODE == 1) {
        for (int i = tid; i < 384; i += 256) {
            if (i < 192) *(float4*)(sm + SS + i * 16) = ((const float4*)scale)[i];
            else         *(float4*)(sm + SH + (i - 192) * 16) = ((const float4*)shift)[i - 192];
        }
    }

    f32x4 acc[4][4];
    #pragma unroll
    for (int i = 0; i < 4; i++)
        #pragma unroll
        for (int j = 0; j < 4; j++) acc[i][j] = (f32x4){0.f, 0.f, 0.f, 0.f};

    float av[2][8];

    auto loadA = [&](int t) {
        #pragma unroll
        for (int q = 0; q < 2; q++) {
            int kb = t * 32 + akb0[q];
            const float* src = A + (size_t)(m0 + ar[q]) * ldA + kb;
            if (kb + 7 < K) {
                *(float4*)&av[q][0] = *(const float4*)src;
                *(float4*)&av[q][4] = *(const float4*)(src + 4);
            } else {
                #pragma unroll
                for (int e = 0; e < 8; e++) av[q][e] = (kb + e < K) ? src[e] : 0.f;
            }
        }
    };
    auto writeA = [&](int t) {
        #pragma unroll
        for (int q = 0; q < 2; q++) {
            int idx = q * 256 + tid;
            float v[8];
            #pragma unroll
            for (int e = 0; e < 8; e++) v[e] = av[q][e];
            if (MODE == 1) {
                int kb = t * 32 + akb0[q];
                float4 sc0 = *(const float4*)(sm + SS + kb * 4);
                float4 sc1 = *(const float4*)(sm + SS + kb * 4 + 16);
                float4 sh0 = *(const float4*)(sm + SH + kb * 4);
                float4 sh1 = *(const float4*)(sm + SH + kb * 4 + 16);
                v[0] = frelu(v[0] * sc0.x + sh0.x); v[1] = frelu(v[1] * sc0.y + sh0.y);
                v[2] = frelu(v[2] * sc0.z + sh0.z); v[3] = frelu(v[3] * sc0.w + sh0.w);
                v[4] = frelu(v[4] * sc1.x + sh1.x); v[5] = frelu(v[5] * sc1.y + sh1.y);
                v[6] = frelu(v[6] * sc1.z + sh1.z); v[7] = frelu(v[7] * sc1.w + sh1.w);
            }
            uint4 o;
            o.x = cvtpk(v[0], v[1]); o.y = cvtpk(v[2], v[3]);
            o.z = cvtpk(v[4], v[5]); o.w = cvtpk(v[6], v[7]);
            *(uint4*)(sm + AH + idx * 16) = o;     // linear write: conflict-free
            if (MODE == 0) {                       // lo residual plane
                float h0 = __builtin_bit_cast(float, o.x << 16);
                float h1 = __builtin_bit_cast(float, o.x & 0xFFFF0000u);
                float h2 = __builtin_bit_cast(float, o.y << 16);
                float h3 = __builtin_bit_cast(float, o.y & 0xFFFF0000u);
                float h4 = __builtin_bit_cast(float, o.z << 16);
                float h5 = __builtin_bit_cast(float, o.z & 0xFFFF0000u);
                float h6 = __builtin_bit_cast(float, o.w << 16);
                float h7 = __builtin_bit_cast(float, o.w & 0xFFFF0000u);
                uint4 p;
                p.x = cvtpk(v[0] - h0, v[1] - h1);
                p.y = cvtpk(v[2] - h2, v[3] - h3);
                p.z = cvtpk(v[4] - h4, v[5] - h5);
                p.w = cvtpk(v[6] - h6, v[7] - h7);
                *(uint4*)(sm + AL + idx * 16) = p;
            }
        }
    };
    auto stageB = [&](int t) {
        size_t cb = (size_t)(nb * NT + t) * 8192;
        #pragma unroll
        for (int q = 0; q < 2; q++) {
            int off = (q * 256 + tid) * 16;
            gload16(BhC + cb + off, sm + BH + off);
            gload16(BlC + cb + off, sm + BL + off);
        }
    };

    loadA(0);
    for (int t = 0; t < NT; t++) {
        __syncthreads();              // readers of previous tile done
        stageB(t);                    // async global->LDS, drains at next barrier
        writeA(t);
        if (t + 1 < NT) loadA(t + 1);
        __syncthreads();              // tile visible
        s16x8 fah[4], fal[4], fbh[4], fbl[4];
        #pragma unroll
        for (int f = 0; f < 4; f++) {
            fah[f] = *(const s16x8*)(sm + AH + aoff[f]);
            fbh[f] = *(const s16x8*)(sm + BH + boff[f]);
            fbl[f] = *(const s16x8*)(sm + BL + boff[f]);
            if (MODE == 0) fal[f] = *(const s16x8*)(sm + AL + aoff[f]);
        }
        #pragma unroll
        for (int i = 0; i < 4; i++)
            #pragma unroll
            for (int j = 0; j < 4; j++) {
                acc[i][j] = __builtin_amdgcn_mfma_f32_16x16x32_bf16(fah[i], fbl[j], acc[i][j], 0, 0, 0);
                if (MODE == 0)
                    acc[i][j] = __builtin_amdgcn_mfma_f32_16x16x32_bf16(fal[i], fbh[j], acc[i][j], 0, 0, 0);
                acc[i][j] = __builtin_amdgcn_mfma_f32_16x16x32_bf16(fah[i], fbh[j], acc[i][j], 0, 0, 0);
            }
    }

    if (MODE == 0) {
        float bc[4];
        #pragma unroll
        for (int f = 0; f < 4; f++) bc[f] = bias[n0 + wc * 64 + f * 16 + l15];
        float cs[4] = {0.f,0.f,0.f,0.f}, cq[4] = {0.f,0.f,0.f,0.f};
        #pragma unroll
        for (int i = 0; i < 4; i++) {
            int rowb = m0 + wr * 64 + i * 16 + l4 * 4;
            #pragma unroll
            for (int j2 = 0; j2 < 4; j2++) {
                float* crow = C + (size_t)(rowb + j2) * HD + n0 + wc * 64 + l15;
                #pragma unroll
                for (int f = 0; f < 4; f++) {
                    float v = acc[i][f][j2] + bc[f];
                    crow[f * 16] = v;
                    cs[f] += v; cq[f] += v * v;
                }
            }
        }
        #pragma unroll
        for (int m = 16; m < 64; m <<= 1)
            #pragma unroll
            for (int f = 0; f < 4; f++) {
                cs[f] += __shfl_xor(cs[f], m, 64);
                cq[f] += __shfl_xor(cq[f], m, 64);
            }
        if (l4 == 0) {
            #pragma unroll
            for (int f = 0; f < 4; f++) {
                int col = n0 + wc * 64 + f * 16 + l15;
                sp1[(size_t)col * 1024 + mb * 2 + wr] = cs[f];
                sp2[(size_t)col * 1024 + mb * 2 + wr] = cq[f];
            }
        }
    } else {
        float bc[4], w2[4][3];
        #pragma unroll
        for (int f = 0; f < 4; f++) {
            int col = n0 + wc * 64 + f * 16 + l15;
            bc[f] = bias[col];
            w2[f][0] = Wd2[col * 3 + 0]; w2[f][1] = Wd2[col * 3 + 1]; w2[f][2] = Wd2[col * 3 + 2];
        }
        float s0[16], s1[16], s2[16];
        #pragma unroll
        for (int i = 0; i < 16; i++) { s0[i] = 0.f; s1[i] = 0.f; s2[i] = 0.f; }
        #pragma unroll
        for (int i = 0; i < 4; i++)
            #pragma unroll
            for (int j2 = 0; j2 < 4; j2++) {
                int idx = i * 4 + j2;
                #pragma unroll
                for (int f = 0; f < 4; f++) {
                    float v = frelu(acc[i][f][j2] + bc[f]);
                    s0[idx] += v * w2[f][0];
                    s1[idx] += v * w2[f][1];
                    s2[idx] += v * w2[f][2];
                }
            }
        #pragma unroll
        for (int m = 1; m < 16; m <<= 1) {
            #pragma unroll
            for (int i = 0; i < 16; i++) {
                s0[i] += __shfl_xor(s0[i], m, 64);
                s1[i] += __shfl_xor(s1[i], m, 64);
                s2[i] += __shfl_xor(s2[i], m, 64);
            }
        }
        if (l15 == 0) {
            #pragma unroll
            for (int i = 0; i < 16; i++) {
                int row = m0 + wr * 64 + (i >> 2) * 16 + l4 * 4 + (i & 3);
                atomicAdd(&domacc[(size_t)row * 3 + 0], (double)s0[i]);
                atomicAdd(&domacc[(size_t)row * 3 + 1], (double)s1[i]);
                atomicAdd(&domacc[(size_t)row * 3 + 2], (double)s2[i]);
            }
        }
    }
}

// ---- BN final: reduce 1024 fp32 partials per column in fp64 ----------------
__global__ __launch_bounds__(256)
void bnfinal(const float* __restrict__ sp1, const float* __restrict__ sp2,
             const float* __restrict__ gamma, const float* __restrict__ beta,
             float* __restrict__ scale, float* __restrict__ shift)
{
    int c = blockIdx.x, t = threadIdx.x;
    const float* p1 = sp1 + (size_t)c * 1024;
    const float* p2 = sp2 + (size_t)c * 1024;
    double S = (double)p1[t] + (double)p1[t + 256] + (double)p1[t + 512] + (double)p1[t + 768];
    double Q = (double)p2[t] + (double)p2[t + 256] + (double)p2[t + 512] + (double)p2[t + 768];
    #pragma unroll
    for (int m = 1; m < 64; m <<= 1) { S += __shfl_xor(S, m, 64); Q += __shfl_xor(Q, m, 64); }
    __shared__ double sd1[4], sd2[4];
    int w = t >> 6;
    if ((t & 63) == 0) { sd1[w] = S; sd2[w] = Q; }
    __syncthreads();
    if (t == 0) {
        double Sa = sd1[0] + sd1[1] + sd1[2] + sd1[3];
        double Qa = sd2[0] + sd2[1] + sd2[2] + sd2[3];
        double mu  = Sa * (1.0 / 65536.0);
        double var = Qa * (1.0 / 65536.0) - mu * mu;
        double inv = 1.0 / sqrt(var + 1e-5);
        double sc  = inv * (double)gamma[c];
        double sh  = (double)beta[c] - mu * sc;
        scale[c] = (float)sc;
        shift[c] = (float)sh;
    }
}

// ---- dom_out finalize pass A: write outdom, flag borderline rows -----------
__global__ __launch_bounds__(256)
void domfinal_a(const double* __restrict__ domacc, const float* __restrict__ bd2,
                float* __restrict__ outdom, int* __restrict__ fixmeta, int* __restrict__ fixlist)
{
    int r = blockIdx.x * 256 + threadIdx.x;
    double v0 = domacc[(size_t)r * 3 + 0] + (double)bd2[0];
    double v1 = domacc[(size_t)r * 3 + 1] + (double)bd2[1];
    double v2 = domacc[(size_t)r * 3 + 2] + (double)bd2[2];
    outdom[(size_t)r * 3 + 0] = (float)v0;
    outdom[(size_t)r * 3 + 1] = (float)v1;
    outdom[(size_t)r * 3 + 2] = (float)v2;
    double mx01 = v0 > v1 ? v0 : v1, mn01 = v0 > v1 ? v1 : v0;
    double best = mx01 > v2 ? mx01 : v2;
    double m2   = mx01 > v2 ? (mn01 > v2 ? mn01 : v2) : mx01;
    if (best - m2 < 8e-3) {
        int p = atomicAdd(fixmeta, 1);
        fixlist[p] = r;
    }
}

// ---- exact fp32 recompute of dom_out for borderline rows (16 rows/block) ---
__global__ __launch_bounds__(256)
void fixrow(const int* __restrict__ fixmeta, const int* __restrict__ fixlist,
            const float* __restrict__ hbuf, const float* __restrict__ scale,
            const float* __restrict__ shift, const float* __restrict__ Wd1,
            const float* __restrict__ bd1, const float* __restrict__ Wd2,
            const float* __restrict__ bd2, float* __restrict__ outdom)
{
    int nfix = fixmeta[0];
    __shared__ float feat[16][HD];
    __shared__ float red[4][3];
    int tid = threadIdx.x;
    for (int base = blockIdx.x * 16; base < nfix; base += gridDim.x * 16) {
        int nr = nfix - base; if (nr > 16) nr = 16;
        __syncthreads();
        for (int i = tid; i < nr * HD; i += 256) {
            int rr = i / HD, c = i - rr * HD;
            int row = fixlist[base + rr];
            feat[rr][c] = frelu(hbuf[(size_t)row * HD + c] * scale[c] + shift[c]);
        }
        __syncthreads();
        int n0 = tid * 3;
        float acc[16][3];
        #pragma unroll
        for (int rr = 0; rr < 16; rr++) { acc[rr][0] = 0.f; acc[rr][1] = 0.f; acc[rr][2] = 0.f; }
        for (int k = 0; k < HD; k++) {
            float w0 = Wd1[(size_t)k * HD + n0];
            float w1 = Wd1[(size_t)k * HD + n0 + 1];
            float w2 = Wd1[(size_t)k * HD + n0 + 2];
            #pragma unroll
            for (int rr = 0; rr < 16; rr++) {
                float fv = feat[rr][k];
                acc[rr][0] += fv * w0; acc[rr][1] += fv * w1; acc[rr][2] += fv * w2;
            }
        }
        float b0 = bd1[n0], b1 = bd1[n0 + 1], b2 = bd1[n0 + 2];
        float wa[3][3];
        #pragma unroll
        for (int i = 0; i < 3; i++)
            #pragma unroll
            for (int d = 0; d < 3; d++) wa[i][d] = Wd2[(n0 + i) * 3 + d];
        #pragma unroll
        for (int rr = 0; rr < 16; rr++) {
            if (rr >= nr) break;
            float h0 = frelu(acc[rr][0] + b0);
            float h1 = frelu(acc[rr][1] + b1);
            float h2 = frelu(acc[rr][2] + b2);
            float y0 = h0 * wa[0][0] + h1 * wa[1][0] + h2 * wa[2][0];
            float y1 = h0 * wa[0][1] + h1 * wa[1][1] + h2 * wa[2][1];
            float y2 = h0 * wa[0][2] + h1 * wa[1][2] + h2 * wa[2][2];
            #pragma unroll
            for (int m = 1; m < 64; m <<= 1) {
                y0 += __shfl_xor(y0, m, 64);
                y1 += __shfl_xor(y1, m, 64);
                y2 += __shfl_xor(y2, m, 64);
            }
            if ((tid & 63) == 0) { red[tid >> 6][0] = y0; red[tid >> 6][1] = y1; red[tid >> 6][2] = y2; }
            __syncthreads();
            if (tid == 0) {
                int row = fixlist[base + rr];
                double v0 = (double)red[0][0] + red[1][0] + red[2][0] + red[3][0] + (double)bd2[0];
                double v1 = (double)red[0][1] + red[1][1] + red[2][1] + red[3][1] + (double)bd2[1];
                double v2 = (double)red[0][2] + red[1][2] + red[2][2] + red[3][2] + (double)bd2[2];
                outdom[(size_t)row * 3 + 0] = (float)v0;
                outdom[(size_t)row * 3 + 1] = (float)v1;
                outdom[(size_t)row * 3 + 2] = (float)v2;
            }
            __syncthreads();
        }
    }
}

// ---- pass B: argmax + bucket. Block-aggregated: 3 global atomics per block -
__global__ __launch_bounds__(256)
void domfinal_b(const float* __restrict__ outdom, int* __restrict__ cnt, int* __restrict__ lists)
{
    __shared__ int lcnt[3], base[3];
    int tid = threadIdx.x;
    if (tid < 3) lcnt[tid] = 0;
    __syncthreads();
    int r = blockIdx.x * 256 + tid;
    float v0 = outdom[(size_t)r * 3 + 0];
    float v1 = outdom[(size_t)r * 3 + 1];
    float v2 = outdom[(size_t)r * 3 + 2];
    int p = 0; float best = v0;
    if (v1 > best) { best = v1; p = 1; }
    if (v2 > best) { best = v2; p = 2; }
    int lpos = atomicAdd(&lcnt[p], 1);
    __syncthreads();
    if (tid < 3) base[tid] = atomicAdd(&cnt[tid], lcnt[tid]);
    __syncthreads();
    lists[(size_t)p * BATCH + base[p] + lpos] = r;
}

// ---- expert MLP: 32 same-domain rows per block, Wa staged through LDS ------
__global__ __launch_bounds__(256)
void expert_kernel(const float* __restrict__ h, const float* __restrict__ scale, const float* __restrict__ shift,
                   const int* __restrict__ cnt, const int* __restrict__ lists,
                   const float* __restrict__ Wa, const float* __restrict__ ba,
                   const float* __restrict__ Wb, const float* __restrict__ bb,
                   float* __restrict__ outs)
{
    int d = blockIdx.y;
    int start = blockIdx.x * 32;
    int count = cnt[d];
    if (start >= count) return;
    int nrows = count - start; if (nrows > 32) nrows = 32;

    __shared__ int   rowidx[32];
    __shared__ float fs[32][68];
    __shared__ float wsa[64][64];
    __shared__ float hid[32][64];

    int tid = threadIdx.x;
    if (tid < 32) {
        int i = tid < nrows ? tid : (nrows - 1);
        rowidx[tid] = lists[(size_t)d * BATCH + start + i];
    }
    __syncthreads();

    int rr = tid >> 3;
    int g  = tid & 7;
    int fcol = g << 3;

    float hacc[8] = {0, 0, 0, 0, 0, 0, 0, 0};

    for (int k0 = 0; k0 < HD; k0 += 64) {
        {
            int row = rowidx[rr];
            const float* hp  = h + (size_t)row * HD + k0 + fcol;
            const float* scp = scale + k0 + fcol;
            const float* shp = shift + k0 + fcol;
            float4 v0 = *(const float4*)hp;
            float4 v1 = *(const float4*)(hp + 4);
            fs[rr][fcol + 0] = frelu(v0.x * scp[0] + shp[0]);
            fs[rr][fcol + 1] = frelu(v0.y * scp[1] + shp[1]);
            fs[rr][fcol + 2] = frelu(v0.z * scp[2] + shp[2]);
            fs[rr][fcol + 3] = frelu(v0.w * scp[3] + shp[3]);
            fs[rr][fcol + 4] = frelu(v1.x * scp[4] + shp[4]);
            fs[rr][fcol + 5] = frelu(v1.y * scp[5] + shp[5]);
            fs[rr][fcol + 6] = frelu(v1.z * scp[6] + shp[6]);
            fs[rr][fcol + 7] = frelu(v1.w * scp[7] + shp[7]);
        }
        #pragma unroll
        for (int rep = 0; rep < 4; rep++) {
            int idx = rep * 256 + tid;
            int kk = idx >> 4;
            int f4 = (idx & 15) << 2;
            *(float4*)&wsa[kk][f4] = *(const float4*)(Wa + ((size_t)d * HD + k0 + kk) * 64 + f4);
        }
        __syncthreads();
        #pragma unroll 8
        for (int kk = 0; kk < 64; kk++) {
            float fv = fs[rr][kk];
            const float* wrow = &wsa[kk][g << 3];
            float4 w0 = *(const float4*)wrow;
            float4 w1 = *(const float4*)(wrow + 4);
            hacc[0] += fv * w0.x; hacc[1] += fv * w0.y; hacc[2] += fv * w0.z; hacc[3] += fv * w0.w;
            hacc[4] += fv * w1.x; hacc[5] += fv * w1.y; hacc[6] += fv * w1.z; hacc[7] += fv * w1.w;
        }
        __syncthreads();
    }

    #pragma unroll
    for (int j = 0; j < 8; j++) {
        float v = hacc[j] + ba[d * 64 + fcol + j];
        hid[rr][fcol + j] = frelu(v);
    }
    __syncthreads();

    for (int o = tid; o < 320; o += 256) {
        int r2 = o / 10, c = o - r2 * 10;
        if (r2 < nrows) {
            float s = 0.f;
            #pragma unroll 16
            for (int l = 0; l < 64; l++) s += hid[r2][l] * Wb[((size_t)d * 64 + l) * 10 + c];
            outs[(size_t)rowidx[r2] * 10 + c] = s + bb[d * 10 + c];
        }
    }
}

// ---------------------------------------------------------------------------
extern "C" void kernel_launch(void* const* d_in, const int* in_sizes, int n_in,
                              void* d_out, int out_size, void* d_ws, size_t ws_size,
                              hipStream_t stream)
{
    const float* x     = (const float*)d_in[0];
    const float* W1    = (const float*)d_in[1];
    const float* b1    = (const float*)d_in[2];
    const float* gamma = (const float*)d_in[3];
    const float* beta  = (const float*)d_in[4];
    const float* Wd1   = (const float*)d_in[5];
    const float* bd1   = (const float*)d_in[6];
    const float* Wd2   = (const float*)d_in[7];
    const float* bd2   = (const float*)d_in[8];
    const float* Wa    = (const float*)d_in[9];
    const float* ba    = (const float*)d_in[10];
    const float* Wb    = (const float*)d_in[11];
    const float* bb    = (const float*)d_in[12];

    float* out    = (float*)d_out;
    float* outs   = out;
    float* outdom = out + (size_t)BATCH * 10;

    const int NT1 = 25, NT2 = 24;

    char* ws = (char*)d_ws;
    size_t off = 0;
    float* h      = (float*)(ws + off);  off += (size_t)BATCH * HD * 4;
    char*  W1hC   = ws + off;            off += (size_t)6 * NT1 * 8192;
    char*  W1lC   = ws + off;            off += (size_t)6 * NT1 * 8192;
    char*  Wd1hC  = ws + off;            off += (size_t)6 * NT2 * 8192;
    char*  Wd1lC  = ws + off;            off += (size_t)6 * NT2 * 8192;
    float* sp1    = (float*)(ws + off);  off += (size_t)HD * 1024 * 4;
    float* sp2    = (float*)(ws + off);  off += (size_t)HD * 1024 * 4;
    float* scale  = (float*)(ws + off);  off += HD * 4;
    float* shift  = (float*)(ws + off);  off += HD * 4;
    size_t zoff = off;
    double* domacc = (double*)(ws + off); off += (size_t)BATCH * 3 * 8;
    int*    cnt    = (int*)(ws + off);    off += 64;
    int*    fixmeta= (int*)(ws + off);    off += 64;
    size_t zbytes = off - zoff;
    int*    lists  = (int*)(ws + off);    off += (size_t)3 * BATCH * 4;
    int*    fixlist= (int*)(ws + off);    off += (size_t)BATCH * 4;

    hipMemsetAsync(ws + zoff, 0, zbytes, stream);

    tileW<<<6 * NT1, 256, 0, stream>>>(W1, W1hC, W1lC, KIN, HD, NT1);
    tileW<<<6 * NT2, 256, 0, stream>>>(Wd1, Wd1hC, Wd1lC, HD, HD, NT2);

    gemm2p<0><<<3072, 256, 0, stream>>>(x, W1hC, W1lC, b1, h,
                                        nullptr, nullptr, nullptr, nullptr,
                                        sp1, sp2, KIN, NT1, KIN);
    bnfinal<<<HD, 256, 0, stream>>>(sp1, sp2, gamma, beta, scale, shift);
    gemm2p<1><<<3072, 256, 0, stream>>>(h, Wd1hC, Wd1lC, bd1, nullptr,
                                        scale, shift, Wd2, domacc,
                                        nullptr, nullptr, HD, NT2, HD);
    domfinal_a<<<BATCH / 256, 256, 0, stream>>>(domacc, bd2, outdom, fixmeta, fixlist);
    fixrow<<<256, 256, 0, stream>>>(fixmeta, fixlist, h, scale, shift, Wd1, bd1, Wd2, bd2, outdom);
    domfinal_b<<<BATCH / 256, 256, 0, stream>>>(outdom, cnt, lists);
    dim3 eg(BATCH / 32, 3);
    expert_kernel<<<eg, 256, 0, stream>>>(h, scale, shift, cnt, lists,
                                          Wa, ba, Wb, bb, outs);
}

// Round 7
// 862.082 us; speedup vs baseline: 1.2522x; 1.0214x over previous
//
#include <hip/hip_runtime.h>
#include <math.h>

#define BATCH 65536
#define KIN   784
#define HD    768

typedef float f32x4 __attribute__((ext_vector_type(4)));
typedef short s16x8 __attribute__((ext_vector_type(8)));
typedef unsigned int __attribute__((address_space(3))) lds_u32;
typedef const unsigned int __attribute__((address_space(1))) glb_u32;

__device__ __forceinline__ float frelu(float x){ return x > 0.f ? x : 0.f; }

// packed bf16 convert: dst = {lo16=cvt(a), hi16=cvt(b)}
__device__ __forceinline__ unsigned int cvtpk(float a, float b){
    unsigned int r;
    asm("v_cvt_pk_bf16_f32 %0, %1, %2" : "=v"(r) : "v"(a), "v"(b));
    return r;
}

__device__ __forceinline__ unsigned short f2bf(float v){
    unsigned int u = __builtin_bit_cast(unsigned int, v);
    u += 0x7FFFu + ((u >> 16) & 1u);
    return (unsigned short)(u >> 16);
}
__device__ __forceinline__ float bf2f(unsigned short s){
    unsigned int u = ((unsigned int)s) << 16;
    return __builtin_bit_cast(float, u);
}

__device__ __forceinline__ void gload16(const void* g, void* l){
    __builtin_amdgcn_global_load_lds((glb_u32*)g, (lds_u32*)l, 16, 0, 0);
}
__device__ __forceinline__ void lgkm0(){ asm volatile("s_waitcnt lgkmcnt(0)" ::: "memory"); }
__device__ __forceinline__ void sfence(){ __builtin_amdgcn_sched_barrier(0); }

// ---------------------------------------------------------------------------
// Pre-tile W[K][N] fp32 into per-(nb,t) 8KB chunks holding the EXACT swizzled
// LDS image: byte (r*64 + p*16 + e*2) of chunk (nb,t) = bf16 of
// W[t*32 + s*8 + e][nb*128 + r], s = p ^ ((r>>1)&3).  hi and lo arrays.
// ---------------------------------------------------------------------------
__global__ __launch_bounds__(256)
void tileW(const float* __restrict__ W, char* __restrict__ Wh, char* __restrict__ Wl,
           int K, int N, int NT)
{
    int chunk = blockIdx.x;
    int nb = chunk / NT, t = chunk - nb * NT;
    int tid = threadIdx.x;
    #pragma unroll
    for (int q = 0; q < 2; q++) {
        int idx = q * 256 + tid;
        int r = idx >> 2, p = idx & 3;
        int s = (p ^ ((r >> 1) & 3)) & 3;
        int kb = t * 32 + s * 8;
        int n = nb * 128 + r;
        s16x8 hv, lv;
        #pragma unroll
        for (int e = 0; e < 8; e++) {
            int k = kb + e;
            float v = (k < K) ? W[(size_t)k * N + n] : 0.f;
            unsigned short h = f2bf(v);
            hv[e] = (short)h;
            lv[e] = (short)f2bf(v - bf2f(h));
        }
        *(s16x8*)(Wh + (size_t)chunk * 8192 + idx * 16) = hv;
        *(s16x8*)(Wl + (size_t)chunk * 8192 + idx * 16) = lv;
    }
}

// ---------------------------------------------------------------------------
// Split-bf16 MFMA GEMM with counted-wait pipeline (T4-style):
//  - B double-buffered via global_load_lds from pre-tiled swizzled chunks;
//    next tile's B + A loads stay IN FLIGHT across the publish barrier
//    (raw s_barrier + lgkmcnt(0) only — no vmcnt drain at barriers).
//  - writeA(t)'s register use of av forces a compiler vmcnt->0 wait that, by
//    vmcnt FIFO semantics, also proves stageB(t) (older) landed — one wait,
//    placed right after a full MFMA phase, so latency is covered.
// MODE 0 (GEMM1): 3-product Ah*Bl + Al*Bh + Ah*Bh (h accurate ~1e-5).
// MODE 1 (GEMM2): 2-product Ah*(Bh+Bl), BN+ReLU fused at A-write.
// ---------------------------------------------------------------------------
template<int MODE>
__global__ __launch_bounds__(256, 3)
void gemm2p(const float* __restrict__ A,
            const char* __restrict__ BhC, const char* __restrict__ BlC,
            const float* __restrict__ bias,
            float* __restrict__ C,
            const float* __restrict__ scale, const float* __restrict__ shift,
            const float* __restrict__ Wd2, double* __restrict__ domacc,
            float* __restrict__ sp1, float* __restrict__ sp2,
            int K, int NT, int ldA)
{
    constexpr int AH = 0;
    constexpr int AL = 8192;                          // MODE 0 only
    constexpr int BB = (MODE == 0) ? 16384 : 8192;    // B dbuf base (2x16KB)
    constexpr int SS = 40960;                         // MODE 1 only
    constexpr int SH = 44032;
    __shared__ __align__(16) char sm[(MODE == 0) ? 49152 : 47104];

    int bid = blockIdx.x;
    int wg = (bid & 7) * 384 + (bid >> 3);      // XCD-contiguous remap
    int mb = wg / 6, nb = wg - mb * 6;
    int m0 = mb << 7, n0 = nb << 7;

    int tid = threadIdx.x;
    int lane = tid & 63, wid = tid >> 6;
    int wr = wid >> 1, wc = wid & 1;
    int l15 = lane & 15, l4 = lane >> 4;

    // fragment LDS byte offsets: logical k-slot l4 at phys slot l4^((row>>1)&3)
    int aoff[4], boff[4];
    #pragma unroll
    for (int f = 0; f < 4; f++) {
        int ra = wr * 64 + f * 16 + l15;
        aoff[f] = ra * 64 + (((l4 ^ (ra >> 1)) & 3) << 4);
        int rb = wc * 64 + f * 16 + l15;
        boff[f] = rb * 64 + (((l4 ^ (rb >> 1)) & 3) << 4);
    }

    // A staging decomposition: idx = q*256+tid covers 512 x 16B groups
    int ar[2], akb0[2];
    #pragma unroll
    for (int q = 0; q < 2; q++) {
        int idx = q * 256 + tid;
        int r = idx >> 2, p = idx & 3;
        int s = (p ^ ((r >> 1) & 3)) & 3;
        ar[q] = r; akb0[q] = s * 8;
    }

    if (MODE == 1) {
        for (int i = tid; i < 384; i += 256) {
            if (i < 192) *(float4*)(sm + SS + i * 16) = ((const float4*)scale)[i];
            else         *(float4*)(sm + SH + (i - 192) * 16) = ((const float4*)shift)[i - 192];
        }
        lgkm0();
        __builtin_amdgcn_s_barrier();   // scale/shift visible before first writeA
    }

    f32x4 acc[4][4];
    #pragma unroll
    for (int i = 0; i < 4; i++)
        #pragma unroll
        for (int j = 0; j < 4; j++) acc[i][j] = (f32x4){0.f, 0.f, 0.f, 0.f};

    float av[2][8];

    auto loadA = [&](int t) {
        #pragma unroll
        for (int q = 0; q < 2; q++) {
            int kb = t * 32 + akb0[q];
            const float* src = A + (size_t)(m0 + ar[q]) * ldA + kb;
            if (kb + 7 < K) {
                *(float4*)&av[q][0] = *(const float4*)src;
                *(float4*)&av[q][4] = *(const float4*)(src + 4);
            } else {
                #pragma unroll
                for (int e = 0; e < 8; e++) av[q][e] = (kb + e < K) ? src[e] : 0.f;
            }
        }
    };
    auto writeA = [&](int t) {
        #pragma unroll
        for (int q = 0; q < 2; q++) {
            int idx = q * 256 + tid;
            float v[8];
            #pragma unroll
            for (int e = 0; e < 8; e++) v[e] = av[q][e];
            if (MODE == 1) {
                int kb = t * 32 + akb0[q];
                float4 sc0 = *(const float4*)(sm + SS + kb * 4);
                float4 sc1 = *(const float4*)(sm + SS + kb * 4 + 16);
                float4 sh0 = *(const float4*)(sm + SH + kb * 4);
                float4 sh1 = *(const float4*)(sm + SH + kb * 4 + 16);
                v[0] = frelu(v[0] * sc0.x + sh0.x); v[1] = frelu(v[1] * sc0.y + sh0.y);
                v[2] = frelu(v[2] * sc0.z + sh0.z); v[3] = frelu(v[3] * sc0.w + sh0.w);
                v[4] = frelu(v[4] * sc1.x + sh1.x); v[5] = frelu(v[5] * sc1.y + sh1.y);
                v[6] = frelu(v[6] * sc1.z + sh1.z); v[7] = frelu(v[7] * sc1.w + sh1.w);
            }
            uint4 o;
            o.x = cvtpk(v[0], v[1]); o.y = cvtpk(v[2], v[3]);
            o.z = cvtpk(v[4], v[5]); o.w = cvtpk(v[6], v[7]);
            *(uint4*)(sm + AH + idx * 16) = o;     // linear write: conflict-free
            if (MODE == 0) {                       // lo residual plane
                float h0 = __builtin_bit_cast(float, o.x << 16);
                float h1 = __builtin_bit_cast(float, o.x & 0xFFFF0000u);
                float h2 = __builtin_bit_cast(float, o.y << 16);
                float h3 = __builtin_bit_cast(float, o.y & 0xFFFF0000u);
                float h4 = __builtin_bit_cast(float, o.z << 16);
                float h5 = __builtin_bit_cast(float, o.z & 0xFFFF0000u);
                float h6 = __builtin_bit_cast(float, o.w << 16);
                float h7 = __builtin_bit_cast(float, o.w & 0xFFFF0000u);
                uint4 p;
                p.x = cvtpk(v[0] - h0, v[1] - h1);
                p.y = cvtpk(v[2] - h2, v[3] - h3);
                p.z = cvtpk(v[4] - h4, v[5] - h5);
                p.w = cvtpk(v[6] - h6, v[7] - h7);
                *(uint4*)(sm + AL + idx * 16) = p;
            }
        }
    };
    auto stageB = [&](int t, int par) {
        size_t cb = (size_t)(nb * NT + t) * 8192;
        char* dst = sm + BB + (par << 14);
        #pragma unroll
        for (int q = 0; q < 2; q++) {
            int off = (q * 256 + tid) * 16;
            gload16(BhC + cb + off, dst + off);
            gload16(BlC + cb + off, dst + 8192 + off);
        }
    };

    loadA(0);
    stageB(0, 0);
    for (int t = 0; t < NT; t++) {
        // consume av(t): compiler must drain vmcnt->0 (FIFO) => stageB(t) also landed
        writeA(t);
        sfence();
        if (t + 1 < NT) { stageB(t + 1, (t + 1) & 1); loadA(t + 1); }
        sfence();
        lgkm0();                          // ds_writes visible; vmem stays in flight
        __builtin_amdgcn_s_barrier();     // publish tile t
        sfence();

        const char* sb = sm + BB + ((t & 1) << 14);
        s16x8 fah[4], fal[4], fbh[4], fbl[4];
        #pragma unroll
        for (int f = 0; f < 4; f++) {
            fah[f] = *(const s16x8*)(sm + AH + aoff[f]);
            fbh[f] = *(const s16x8*)(sb + boff[f]);
            fbl[f] = *(const s16x8*)(sb + 8192 + boff[f]);
            if (MODE == 0) fal[f] = *(const s16x8*)(sm + AL + aoff[f]);
        }
        #pragma unroll
        for (int i = 0; i < 4; i++)
            #pragma unroll
            for (int j = 0; j < 4; j++) {
                acc[i][j] = __builtin_amdgcn_mfma_f32_16x16x32_bf16(fah[i], fbl[j], acc[i][j], 0, 0, 0);
                if (MODE == 0)
                    acc[i][j] = __builtin_amdgcn_mfma_f32_16x16x32_bf16(fal[i], fbh[j], acc[i][j], 0, 0, 0);
                acc[i][j] = __builtin_amdgcn_mfma_f32_16x16x32_bf16(fah[i], fbh[j], acc[i][j], 0, 0, 0);
            }
        sfence();
        lgkm0();                          // my LDS reads complete
        __builtin_amdgcn_s_barrier();     // all readers done -> next writeA safe
        sfence();
    }

    if (MODE == 0) {
        float bc[4];
        #pragma unroll
        for (int f = 0; f < 4; f++) bc[f] = bias[n0 + wc * 64 + f * 16 + l15];
        float cs[4] = {0.f,0.f,0.f,0.f}, cq[4] = {0.f,0.f,0.f,0.f};
        #pragma unroll
        for (int i = 0; i < 4; i++) {
            int rowb = m0 + wr * 64 + i * 16 + l4 * 4;
            #pragma unroll
            for (int j2 = 0; j2 < 4; j2++) {
                float* crow = C + (size_t)(rowb + j2) * HD + n0 + wc * 64 + l15;
                #pragma unroll
                for (int f = 0; f < 4; f++) {
                    float v = acc[i][f][j2] + bc[f];
                    crow[f * 16] = v;
                    cs[f] += v; cq[f] += v * v;
                }
            }
        }
        #pragma unroll
        for (int m = 16; m < 64; m <<= 1)
            #pragma unroll
            for (int f = 0; f < 4; f++) {
                cs[f] += __shfl_xor(cs[f], m, 64);
                cq[f] += __shfl_xor(cq[f], m, 64);
            }
        if (l4 == 0) {
            #pragma unroll
            for (int f = 0; f < 4; f++) {
                int col = n0 + wc * 64 + f * 16 + l15;
                sp1[(size_t)col * 1024 + mb * 2 + wr] = cs[f];
                sp2[(size_t)col * 1024 + mb * 2 + wr] = cq[f];
            }
        }
    } else {
        float bc[4], w2[4][3];
        #pragma unroll
        for (int f = 0; f < 4; f++) {
            int col = n0 + wc * 64 + f * 16 + l15;
            bc[f] = bias[col];
            w2[f][0] = Wd2[col * 3 + 0]; w2[f][1] = Wd2[col * 3 + 1]; w2[f][2] = Wd2[col * 3 + 2];
        }
        float s0[16], s1[16], s2[16];
        #pragma unroll
        for (int i = 0; i < 16; i++) { s0[i] = 0.f; s1[i] = 0.f; s2[i] = 0.f; }
        #pragma unroll
        for (int i = 0; i < 4; i++)
            #pragma unroll
            for (int j2 = 0; j2 < 4; j2++) {
                int idx = i * 4 + j2;
                #pragma unroll
                for (int f = 0; f < 4; f++) {
                    float v = frelu(acc[i][f][j2] + bc[f]);
                    s0[idx] += v * w2[f][0];
                    s1[idx] += v * w2[f][1];
                    s2[idx] += v * w2[f][2];
                }
            }
        #pragma unroll
        for (int m = 1; m < 16; m <<= 1) {
            #pragma unroll
            for (int i = 0; i < 16; i++) {
                s0[i] += __shfl_xor(s0[i], m, 64);
                s1[i] += __shfl_xor(s1[i], m, 64);
                s2[i] += __shfl_xor(s2[i], m, 64);
            }
        }
        if (l15 == 0) {
            #pragma unroll
            for (int i = 0; i < 16; i++) {
                int row = m0 + wr * 64 + (i >> 2) * 16 + l4 * 4 + (i & 3);
                atomicAdd(&domacc[(size_t)row * 3 + 0], (double)s0[i]);
                atomicAdd(&domacc[(size_t)row * 3 + 1], (double)s1[i]);
                atomicAdd(&domacc[(size_t)row * 3 + 2], (double)s2[i]);
            }
        }
    }
}

// ---- BN final: reduce 1024 fp32 partials per column in fp64 ----------------
__global__ __launch_bounds__(256)
void bnfinal(const float* __restrict__ sp1, const float* __restrict__ sp2,
             const float* __restrict__ gamma, const float* __restrict__ beta,
             float* __restrict__ scale, float* __restrict__ shift)
{
    int c = blockIdx.x, t = threadIdx.x;
    const float* p1 = sp1 + (size_t)c * 1024;
    const float* p2 = sp2 + (size_t)c * 1024;
    double S = (double)p1[t] + (double)p1[t + 256] + (double)p1[t + 512] + (double)p1[t + 768];
    double Q = (double)p2[t] + (double)p2[t + 256] + (double)p2[t + 512] + (double)p2[t + 768];
    #pragma unroll
    for (int m = 1; m < 64; m <<= 1) { S += __shfl_xor(S, m, 64); Q += __shfl_xor(Q, m, 64); }
    __shared__ double sd1[4], sd2[4];
    int w = t >> 6;
    if ((t & 63) == 0) { sd1[w] = S; sd2[w] = Q; }
    __syncthreads();
    if (t == 0) {
        double Sa = sd1[0] + sd1[1] + sd1[2] + sd1[3];
        double Qa = sd2[0] + sd2[1] + sd2[2] + sd2[3];
        double mu  = Sa * (1.0 / 65536.0);
        double var = Qa * (1.0 / 65536.0) - mu * mu;
        double inv = 1.0 / sqrt(var + 1e-5);
        double sc  = inv * (double)gamma[c];
        double sh  = (double)beta[c] - mu * sc;
        scale[c] = (float)sc;
        shift[c] = (float)sh;
    }
}

// ---- dom_out finalize pass A: write outdom, flag borderline rows -----------
__global__ __launch_bounds__(256)
void domfinal_a(const double* __restrict__ domacc, const float* __restrict__ bd2,
                float* __restrict__ outdom, int* __restrict__ fixmeta, int* __restrict__ fixlist)
{
    int r = blockIdx.x * 256 + threadIdx.x;
    double v0 = domacc[(size_t)r * 3 + 0] + (double)bd2[0];
    double v1 = domacc[(size_t)r * 3 + 1] + (double)bd2[1];
    double v2 = domacc[(size_t)r * 3 + 2] + (double)bd2[2];
    outdom[(size_t)r * 3 + 0] = (float)v0;
    outdom[(size_t)r * 3 + 1] = (float)v1;
    outdom[(size_t)r * 3 + 2] = (float)v2;
    double mx01 = v0 > v1 ? v0 : v1, mn01 = v0 > v1 ? v1 : v0;
    double best = mx01 > v2 ? mx01 : v2;
    double m2   = mx01 > v2 ? (mn01 > v2 ? mn01 : v2) : mx01;
    if (best - m2 < 8e-3) {
        int p = atomicAdd(fixmeta, 1);
        fixlist[p] = r;
    }
}

// ---- exact fp32 recompute of dom_out for borderline rows (16 rows/block) ---
__global__ __launch_bounds__(256)
void fixrow(const int* __restrict__ fixmeta, const int* __restrict__ fixlist,
            const float* __restrict__ hbuf, const float* __restrict__ scale,
            const float* __restrict__ shift, const float* __restrict__ Wd1,
            const float* __restrict__ bd1, const float* __restrict__ Wd2,
            const float* __restrict__ bd2, float* __restrict__ outdom)
{
    int nfix = fixmeta[0];
    __shared__ float feat[16][HD];
    __shared__ float red[4][3];
    int tid = threadIdx.x;
    for (int base = blockIdx.x * 16; base < nfix; base += gridDim.x * 16) {
        int nr = nfix - base; if (nr > 16) nr = 16;
        __syncthreads();
        for (int i = tid; i < nr * HD; i += 256) {
            int rr = i / HD, c = i - rr * HD;
            int row = fixlist[base + rr];
            feat[rr][c] = frelu(hbuf[(size_t)row * HD + c] * scale[c] + shift[c]);
        }
        __syncthreads();
        int n0 = tid * 3;
        float acc[16][3];
        #pragma unroll
        for (int rr = 0; rr < 16; rr++) { acc[rr][0] = 0.f; acc[rr][1] = 0.f; acc[rr][2] = 0.f; }
        for (int k = 0; k < HD; k++) {
            float w0 = Wd1[(size_t)k * HD + n0];
            float w1 = Wd1[(size_t)k * HD + n0 + 1];
            float w2 = Wd1[(size_t)k * HD + n0 + 2];
            #pragma unroll
            for (int rr = 0; rr < 16; rr++) {
                float fv = feat[rr][k];
                acc[rr][0] += fv * w0; acc[rr][1] += fv * w1; acc[rr][2] += fv * w2;
            }
        }
        float b0 = bd1[n0], b1 = bd1[n0 + 1], b2 = bd1[n0 + 2];
        float wa[3][3];
        #pragma unroll
        for (int i = 0; i < 3; i++)
            #pragma unroll
            for (int d = 0; d < 3; d++) wa[i][d] = Wd2[(n0 + i) * 3 + d];
        #pragma unroll
        for (int rr = 0; rr < 16; rr++) {
            if (rr >= nr) break;
            float h0 = frelu(acc[rr][0] + b0);
            float h1 = frelu(acc[rr][1] + b1);
            float h2 = frelu(acc[rr][2] + b2);
            float y0 = h0 * wa[0][0] + h1 * wa[1][0] + h2 * wa[2][0];
            float y1 = h0 * wa[0][1] + h1 * wa[1][1] + h2 * wa[2][1];
            float y2 = h0 * wa[0][2] + h1 * wa[1][2] + h2 * wa[2][2];
            #pragma unroll
            for (int m = 1; m < 64; m <<= 1) {
                y0 += __shfl_xor(y0, m, 64);
                y1 += __shfl_xor(y1, m, 64);
                y2 += __shfl_xor(y2, m, 64);
            }
            if ((tid & 63) == 0) { red[tid >> 6][0] = y0; red[tid >> 6][1] = y1; red[tid >> 6][2] = y2; }
            __syncthreads();
            if (tid == 0) {
                int row = fixlist[base + rr];
                double v0 = (double)red[0][0] + red[1][0] + red[2][0] + red[3][0] + (double)bd2[0];
                double v1 = (double)red[0][1] + red[1][1] + red[2][1] + red[3][1] + (double)bd2[1];
                double v2 = (double)red[0][2] + red[1][2] + red[2][2] + red[3][2] + (double)bd2[2];
                outdom[(size_t)row * 3 + 0] = (float)v0;
                outdom[(size_t)row * 3 + 1] = (float)v1;
                outdom[(size_t)row * 3 + 2] = (float)v2;
            }
            __syncthreads();
        }
    }
}

// ---- pass B: argmax + bucket. Block-aggregated: 3 global atomics per block -
__global__ __launch_bounds__(256)
void domfinal_b(const float* __restrict__ outdom, int* __restrict__ cnt, int* __restrict__ lists)
{
    __shared__ int lcnt[3], base[3];
    int tid = threadIdx.x;
    if (tid < 3) lcnt[tid] = 0;
    __syncthreads();
    int r = blockIdx.x * 256 + tid;
    float v0 = outdom[(size_t)r * 3 + 0];
    float v1 = outdom[(size_t)r * 3 + 1];
    float v2 = outdom[(size_t)r * 3 + 2];
    int p = 0; float best = v0;
    if (v1 > best) { best = v1; p = 1; }
    if (v2 > best) { best = v2; p = 2; }
    int lpos = atomicAdd(&lcnt[p], 1);
    __syncthreads();
    if (tid < 3) base[tid] = atomicAdd(&cnt[tid], lcnt[tid]);
    __syncthreads();
    lists[(size_t)p * BATCH + base[p] + lpos] = r;
}

// ---- expert MLP: 32 same-domain rows per block, Wa staged through LDS ------
__global__ __launch_bounds__(256)
void expert_kernel(const float* __restrict__ h, const float* __restrict__ scale, const float* __restrict__ shift,
                   const int* __restrict__ cnt, const int* __restrict__ lists,
                   const float* __restrict__ Wa, const float* __restrict__ ba,
                   const float* __restrict__ Wb, const float* __restrict__ bb,
                   float* __restrict__ outs)
{
    int d = blockIdx.y;
    int start = blockIdx.x * 32;
    int count = cnt[d];
    if (start >= count) return;
    int nrows = count - start; if (nrows > 32) nrows = 32;

    __shared__ int   rowidx[32];
    __shared__ float fs[32][68];
    __shared__ float wsa[64][64];
    __shared__ float hid[32][64];

    int tid = threadIdx.x;
    if (tid < 32) {
        int i = tid < nrows ? tid : (nrows - 1);
        rowidx[tid] = lists[(size_t)d * BATCH + start + i];
    }
    __syncthreads();

    int rr = tid >> 3;
    int g  = tid & 7;
    int fcol = g << 3;

    float hacc[8] = {0, 0, 0, 0, 0, 0, 0, 0};

    for (int k0 = 0; k0 < HD; k0 += 64) {
        {
            int row = rowidx[rr];
            const float* hp  = h + (size_t)row * HD + k0 + fcol;
            const float* scp = scale + k0 + fcol;
            const float* shp = shift + k0 + fcol;
            float4 v0 = *(const float4*)hp;
            float4 v1 = *(const float4*)(hp + 4);
            fs[rr][fcol + 0] = frelu(v0.x * scp[0] + shp[0]);
            fs[rr][fcol + 1] = frelu(v0.y * scp[1] + shp[1]);
            fs[rr][fcol + 2] = frelu(v0.z * scp[2] + shp[2]);
            fs[rr][fcol + 3] = frelu(v0.w * scp[3] + shp[3]);
            fs[rr][fcol + 4] = frelu(v1.x * scp[4] + shp[4]);
            fs[rr][fcol + 5] = frelu(v1.y * scp[5] + shp[5]);
            fs[rr][fcol + 6] = frelu(v1.z * scp[6] + shp[6]);
            fs[rr][fcol + 7] = frelu(v1.w * scp[7] + shp[7]);
        }
        #pragma unroll
        for (int rep = 0; rep < 4; rep++) {
            int idx = rep * 256 + tid;
            int kk = idx >> 4;
            int f4 = (idx & 15) << 2;
            *(float4*)&wsa[kk][f4] = *(const float4*)(Wa + ((size_t)d * HD + k0 + kk) * 64 + f4);
        }
        __syncthreads();
        #pragma unroll 8
        for (int kk = 0; kk < 64; kk++) {
            float fv = fs[rr][kk];
            const float* wrow = &wsa[kk][g << 3];
            float4 w0 = *(const float4*)wrow;
            float4 w1 = *(const float4*)(wrow + 4);
            hacc[0] += fv * w0.x; hacc[1] += fv * w0.y; hacc[2] += fv * w0.z; hacc[3] += fv * w0.w;
            hacc[4] += fv * w1.x; hacc[5] += fv * w1.y; hacc[6] += fv * w1.z; hacc[7] += fv * w1.w;
        }
        __syncthreads();
    }

    #pragma unroll
    for (int j = 0; j < 8; j++) {
        float v = hacc[j] + ba[d * 64 + fcol + j];
        hid[rr][fcol + j] = frelu(v);
    }
    __syncthreads();

    for (int o = tid; o < 320; o += 256) {
        int r2 = o / 10, c = o - r2 * 10;
        if (r2 < nrows) {
            float s = 0.f;
            #pragma unroll 16
            for (int l = 0; l < 64; l++) s += hid[r2][l] * Wb[((size_t)d * 64 + l) * 10 + c];
            outs[(size_t)rowidx[r2] * 10 + c] = s + bb[d * 10 + c];
        }
    }
}

// ---------------------------------------------------------------------------
extern "C" void kernel_launch(void* const* d_in, const int* in_sizes, int n_in,
                              void* d_out, int out_size, void* d_ws, size_t ws_size,
                              hipStream_t stream)
{
    const float* x     = (const float*)d_in[0];
    const float* W1    = (const float*)d_in[1];
    const float* b1    = (const float*)d_in[2];
    const float* gamma = (const float*)d_in[3];
    const float* beta  = (const float*)d_in[4];
    const float* Wd1   = (const float*)d_in[5];
    const float* bd1   = (const float*)d_in[6];
    const float* Wd2   = (const float*)d_in[7];
    const float* bd2   = (const float*)d_in[8];
    const float* Wa    = (const float*)d_in[9];
    const float* ba    = (const float*)d_in[10];
    const float* Wb    = (const float*)d_in[11];
    const float* bb    = (const float*)d_in[12];

    float* out    = (float*)d_out;
    float* outs   = out;
    float* outdom = out + (size_t)BATCH * 10;

    const int NT1 = 25, NT2 = 24;

    char* ws = (char*)d_ws;
    size_t off = 0;
    float* h      = (float*)(ws + off);  off += (size_t)BATCH * HD * 4;
    char*  W1hC   = ws + off;            off += (size_t)6 * NT1 * 8192;
    char*  W1lC   = ws + off;            off += (size_t)6 * NT1 * 8192;
    char*  Wd1hC  = ws + off;            off += (size_t)6 * NT2 * 8192;
    char*  Wd1lC  = ws + off;            off += (size_t)6 * NT2 * 8192;
    float* sp1    = (float*)(ws + off);  off += (size_t)HD * 1024 * 4;
    float* sp2    = (float*)(ws + off);  off += (size_t)HD * 1024 * 4;
    float* scale  = (float*)(ws + off);  off += HD * 4;
    float* shift  = (float*)(ws + off);  off += HD * 4;
    size_t zoff = off;
    double* domacc = (double*)(ws + off); off += (size_t)BATCH * 3 * 8;
    int*    cnt    = (int*)(ws + off);    off += 64;
    int*    fixmeta= (int*)(ws + off);    off += 64;
    size_t zbytes = off - zoff;
    int*    lists  = (int*)(ws + off);    off += (size_t)3 * BATCH * 4;
    int*    fixlist= (int*)(ws + off);    off += (size_t)BATCH * 4;

    hipMemsetAsync(ws + zoff, 0, zbytes, stream);

    tileW<<<6 * NT1, 256, 0, stream>>>(W1, W1hC, W1lC, KIN, HD, NT1);
    tileW<<<6 * NT2, 256, 0, stream>>>(Wd1, Wd1hC, Wd1lC, HD, HD, NT2);

    gemm2p<0><<<3072, 256, 0, stream>>>(x, W1hC, W1lC, b1, h,
                                        nullptr, nullptr, nullptr, nullptr,
                                        sp1, sp2, KIN, NT1, KIN);
    bnfinal<<<HD, 256, 0, stream>>>(sp1, sp2, gamma, beta, scale, shift);
    gemm2p<1><<<3072, 256, 0, stream>>>(h, Wd1hC, Wd1lC, bd1, nullptr,
                                        scale, shift, Wd2, domacc,
                                        nullptr, nullptr, HD, NT2, HD);
    domfinal_a<<<BATCH / 256, 256, 0, stream>>>(domacc, bd2, outdom, fixmeta, fixlist);
    fixrow<<<256, 256, 0, stream>>>(fixmeta, fixlist, h, scale, shift, Wd1, bd1, Wd2, bd2, outdom);
    domfinal_b<<<BATCH / 256, 256, 0, stream>>>(outdom, cnt, lists);
    dim3 eg(BATCH / 32, 3);
    expert_kernel<<<eg, 256, 0, stream>>>(h, scale, shift, cnt, lists,
                                          Wa, ba, Wb, bb, outs);
}